// Round 15
// baseline (666.343 us; speedup 1.0000x reference)
//
#include <hip/hip_runtime.h>
#include <math.h>

#define Bn 8
#define Cn 64
#define Hn 96
#define Wn 96
#define HWn (Hn*Wn)
#define OCn 64
#define Kn 9
#define OFFCn 27
#define NPIX (Bn*HWn)        // 73728 = 1152*64
#define PGRPS (NPIX/64)      // 1152 pixel groups
#define BLK_PER_B (HWn/64)   // 144 blocks per batch image = PGRPS/8
#define WROWS 12             // staged row window
#define WPLANE (WROWS*Wn)    // 1152 floats per staged channel

// ws layout (dwords): wpk1[15552] | wpk2m[131072 shorts]
#define WPK1_N 15552
#define WPK2M_SHORTS 131072
#define WS_DWORDS (WPK1_N + WPK2M_SHORTS/2)
#define WS_BYTES  ((size_t)WS_DWORDS*4)   // ~320 KB

typedef __attribute__((ext_vector_type(8))) short short8v;
typedef __attribute__((ext_vector_type(4))) float f32x4;

static __device__ __forceinline__ unsigned short bf16_rne(float f) {
    unsigned int u = __float_as_uint(f);
    return (unsigned short)((u + 0x7FFFu + ((u >> 16) & 1u)) >> 16);
}
static __device__ __forceinline__ float bf16_back(unsigned short h) {
    return __uint_as_float(((unsigned int)h) << 16);
}

// ============ wprep: wpk1 stream (offset conv) + wpk2m MFMA A-frags ===========
__global__ __launch_bounds__(256) void dcn_wprep(
    const float* __restrict__ w_off,
    const float* __restrict__ weight,
    float* __restrict__ wpk1,
    short* __restrict__ wpk2m)
{
    const int g = blockIdx.x * 256 + threadIdx.x;   // 64 blocks -> 16384
    if (g < WPK1_N) {
        const int c_all = g / 243;
        const int och   = (g % 243) / 9;
        const int ki    = g % 9;
        wpk1[g] = w_off[(och * 64 + c_all) * 9 + ki];
    }
    if (g < WPK2M_SHORTS / 8) {
        const int lane = g & 63;
        const int oct  = (g >> 6) & 3;
        const int c    = g >> 8;
        const int oc   = oct * 16 + (lane & 15);
        const float* wsrc = weight + (oc * 64 + c) * 9;
        short8v v;
#pragma unroll
        for (int j = 0; j < 8; ++j) {
            const int s = ((lane >> 4) & 3) * 8 + j;
            float f = 0.0f;
            if (s <= 8)                  f = wsrc[s];
            else if (s >= 16 && s <= 24) f = wsrc[s - 16];
            v[j] = (short)bf16_rne(f);
        }
        ((short8v*)wpk2m)[g] = v;
    }
}

// ====== fused: LDS-staged x window -> offset conv -> gather -> MFMA ===========
// R15: all bilinear gathers moved from scattered global VMEM (the measured
// bottleneck: time ~ scattered-load count, R7/R12/R13 evidence) to LDS.
// 12-row x-window per 8-channel chunk staged with coalesced float4 loads.
// Out-of-window samples (offsets beyond ~3 rows, >>12 sigma) fall back to the
// global path per wave via __all.
__global__ __launch_bounds__(256, 2) void dcn_fused(
    const float* __restrict__ x,
    const float* __restrict__ wpk1,
    const float* __restrict__ b_off,
    const short* __restrict__ wpk2m,
    const float* __restrict__ bias,
    float* __restrict__ out)
{
    __shared__ float xstage[8 * WPLANE];    // 36864 B
    __shared__ short smp[32 * 64 * 8];      // 32768 B; phase-1 reduce aliases
    float* lds1 = (float*)smp;              // 27648 B needed <= 32768

    const int tid  = threadIdx.x;
    const int lane = tid & 63;
    const int wv   = tid >> 6;

    // XCD swizzle (1152 = 8 * 144, one image per XCD) -- R14-proven (FETCH 8x)
    const int bid = (blockIdx.x & 7) * BLK_PER_B + (blockIdx.x >> 3);

    const int p0  = bid * 64;
    const int b   = p0 / HWn;
    const int hwb = p0 % HWn;
    const int p   = p0 + lane;
    const int hw  = p % HWn;
    const int ho  = hw / Wn;
    const int wo  = hw % Wn;

    const float* xb = x + b * (Cn * HWn);

    // staged window rows [rw, rw+11] (block-uniform)
    const int r0   = hwb / Wn;
    const int rw   = min(max(r0 - 4, 0), Hn - WROWS);
    const int rw96 = rw * Wn;

    // cooperative stage: thread group (sc,st) copies channel sc's window
    const int sc = tid >> 5;          // 0..7
    const int st = tid & 31;          // 0..31

    // ---------------- static 3x3 taps in window coords ------------------------
    int   ltoff[Kn];
    float tval[Kn];
#pragma unroll
    for (int ki = 0; ki < Kn; ++ki) {
        const int yy = ho + ki / 3 - 1, xx = wo + ki % 3 - 1;
        const bool v = (yy >= 0) && (yy < Hn) && (xx >= 0) && (xx < Wn);
        ltoff[ki] = min(max(yy, 0), Hn - 1) * Wn + min(max(xx, 0), Wn - 1) - rw96;
        tval[ki] = v ? 1.0f : 0.0f;
    }

    // ---------------- Phase 1: offset conv from staged LDS --------------------
    float om[OFFCn];
#pragma unroll
    for (int j = 0; j < OFFCn; ++j) om[j] = 0.0f;

    for (int chunk = 0; chunk < 8; ++chunk) {
        {   // stage 8 channels' windows (coalesced float4)
            const float4* src = (const float4*)(xb + (chunk * 8 + sc) * HWn + rw96);
            float4* dst = (float4*)(xstage + sc * WPLANE);
#pragma unroll
            for (int i = 0; i < 9; ++i) dst[st + 32 * i] = src[st + 32 * i];
        }
        __syncthreads();

#pragma unroll
        for (int cc = 0; cc < 2; ++cc) {
            const int cl = wv * 2 + cc;
            const int c  = chunk * 8 + cl;
            const float* xs = xstage + cl * WPLANE;
            float xk[Kn];
#pragma unroll
            for (int ki = 0; ki < Kn; ++ki)
                xk[ki] = xs[ltoff[ki]] * tval[ki];

            const float* wc = wpk1 + c * 243;        // contiguous per channel
#pragma unroll
            for (int och = 0; och < OFFCn; ++och) {
                const float* wp = wc + och * 9;
                float a = om[och];
#pragma unroll
                for (int ki = 0; ki < Kn; ++ki)
                    a = fmaf(xk[ki], wp[ki], a);
                om[och] = a;
            }
        }
        __syncthreads();   // before next stage overwrites xstage
    }

    // LDS reduce (stride 27 dwords, gcd(27,32)=1 -> conflict-free)
#pragma unroll
    for (int j = 0; j < OFFCn; ++j)
        lds1[(wv * 64 + lane) * OFFCn + j] = om[j];
    __syncthreads();
#pragma unroll
    for (int j = 0; j < OFFCn; ++j) {
        float a = b_off[j];
#pragma unroll
        for (int ww = 0; ww < 4; ++ww)
            a += lds1[(ww * 64 + lane) * OFFCn + j];
        om[j] = a;
    }

    // ---------------- Phase 1.5: sampling params + window mask ----------------
    float pw0[Kn], pw1[Kn], pw2[Kn], pw3[Kn];
    int   pav[Kn];
    int   okm = 0;
#pragma unroll
    for (int ki = 0; ki < Kn; ++ki) {
        const float py = om[ki]      + (float)(ki / 3 + ho - 1);
        const float px = om[Kn + ki] + (float)(ki % 3 + wo - 1);
        const float m  = 1.0f / (1.0f + __expf(-om[2 * Kn + ki]));

        const float y0f = floorf(py), x0f = floorf(px);
        const float ly = py - y0f, lx = px - x0f;
        const int iy0 = (int)y0f, ix0 = (int)x0f;
        const int iy1 = iy0 + 1,  ix1 = ix0 + 1;

        const float vy0 = (iy0 >= 0 && iy0 < Hn) ? 1.0f : 0.0f;
        const float vy1 = (iy1 >= 0 && iy1 < Hn) ? 1.0f : 0.0f;
        const float vx0 = (ix0 >= 0 && ix0 < Wn) ? 1.0f : 0.0f;
        const float vx1 = (ix1 >= 0 && ix1 < Wn) ? 1.0f : 0.0f;

        const int iy0c = min(max(iy0, 0), Hn - 1);
        const int iy1c = min(max(iy1, 0), Hn - 1);
        const int ix0c = min(max(ix0, 0), Wn - 1);
        const int ix1c = min(max(ix1, 0), Wn - 1);

        pw0[ki] = m * (1.0f - ly) * (1.0f - lx) * vy0 * vx0;
        pw1[ki] = m * (1.0f - ly) * lx          * vy0 * vx1;
        pw2[ki] = m * ly          * (1.0f - lx) * vy1 * vx0;
        pw3[ki] = m * ly          * lx          * vy1 * vx1;
        const int pa  = iy0c * Wn + ix0c;
        const int dx  = ix1c - ix0c;
        const int dyw = (iy1c - iy0c) * Wn;
        pav[ki] = pa | (dx << 16) | (dyw << 17);

        const int lpa = pa - rw96;
        const int ok  = (lpa >= 0) && (lpa + dyw + dx < WPLANE);
        okm |= ok << ki;
    }
    __syncthreads();   // lds1 reads done before smp is overwritten

    // ---------------- Phase 2: stage -> LDS gather -> MFMA --------------------
    f32x4 acc[4];
#pragma unroll
    for (int oct = 0; oct < 4; ++oct) acc[oct] = (f32x4){0.f, 0.f, 0.f, 0.f};

    const short8v* afrags = (const short8v*)wpk2m;
    const int fastpath = __all(okm == 0x1FF);

    {   // stage chunk 0
        const float4* src = (const float4*)(xb + sc * HWn + rw96);
        float4* dst = (float4*)(xstage + sc * WPLANE);
#pragma unroll
        for (int i = 0; i < 9; ++i) dst[st + 32 * i] = src[st + 32 * i];
    }
    __syncthreads();

    for (int chunk = 0; chunk < 8; ++chunk) {
        // ---- gather: wave wv samples channels chunk*8 + wv*2 + {0,1} ----
#pragma unroll
        for (int cc = 0; cc < 2; ++cc) {
            const int cl = (wv << 1) | cc;
            unsigned short hi[Kn], lo[Kn];
            if (fastpath) {
                const float* xs = xstage + cl * WPLANE - rw96;   // index by pa
#pragma unroll
                for (int ki = 0; ki < Kn; ++ki) {
                    const int av  = pav[ki];
                    const int pa  = av & 0xFFFF;
                    const int dx  = (av >> 16) & 1;
                    const int dyw = av >> 17;
                    const float* bp = xs + pa;
                    const float v = pw0[ki] * bp[0] + pw1[ki] * bp[dx]
                                  + pw2[ki] * bp[dyw] + pw3[ki] * bp[dyw + dx];
                    hi[ki] = bf16_rne(v);
                    lo[ki] = bf16_rne(v - bf16_back(hi[ki]));
                }
            } else {
                const float* xc = xb + (chunk * 8 + cl) * HWn;
#pragma unroll
                for (int ki = 0; ki < Kn; ++ki) {
                    const int av  = pav[ki];
                    const int pa  = av & 0xFFFF;
                    const int dx  = (av >> 16) & 1;
                    const int dyw = av >> 17;
                    const float* bp = xc + pa;
                    const float v = pw0[ki] * bp[0] + pw1[ki] * bp[dx]
                                  + pw2[ki] * bp[dyw] + pw3[ki] * bp[dyw + dx];
                    hi[ki] = bf16_rne(v);
                    lo[ki] = bf16_rne(v - bf16_back(hi[ki]));
                }
            }
            short8v h0, h1, l0, l1;
#pragma unroll
            for (int j = 0; j < 8; ++j) { h0[j] = (short)hi[j]; l0[j] = (short)lo[j]; }
            h1 = (short8v){(short)hi[8], 0, 0, 0, 0, 0, 0, 0};
            l1 = (short8v){(short)lo[8], 0, 0, 0, 0, 0, 0, 0};
            const int r0s = cl * 4;
            *(short8v*)&smp[((r0s + 0) * 64 + lane) * 8] = h0;
            *(short8v*)&smp[((r0s + 1) * 64 + lane) * 8] = h1;
            *(short8v*)&smp[((r0s + 2) * 64 + lane) * 8] = l0;
            *(short8v*)&smp[((r0s + 3) * 64 + lane) * 8] = l1;
        }
        __syncthreads();

        // ---- stage next chunk (overlaps MFMA; xstage not read by MFMA) ----
        if (chunk < 7) {
            const float4* src = (const float4*)(xb + ((chunk + 1) * 8 + sc) * HWn + rw96);
            float4* dst = (float4*)(xstage + sc * WPLANE);
#pragma unroll
            for (int i = 0; i < 9; ++i) dst[st + 32 * i] = src[st + 32 * i];
        }

        // ---- MFMA: ks == channel-in-chunk; B reused across 4 oc-tiles ----
#pragma unroll
        for (int ks = 0; ks < 8; ++ks) {
            const short8v bfrag = *(const short8v*)
                &smp[((ks * 4 + (lane >> 4)) * 64 + wv * 16 + (lane & 15)) * 8];
#pragma unroll
            for (int oct = 0; oct < 4; ++oct) {
                const short8v afrag =
                    afrags[(((chunk * 8 + ks) * 4) + oct) * 64 + lane];
                acc[oct] = __builtin_amdgcn_mfma_f32_16x16x32_bf16(
                    afrag, bfrag, acc[oct], 0, 0, 0);
            }
        }
        __syncthreads();
    }

    // ---------------- epilogue: C col=lane&15 -> px, row=(lane>>4)*4+r -> oc --
    const int pxl = wv * 16 + (lane & 15);
    float* ob = out + b * (OCn * HWn) + hwb + pxl;
#pragma unroll
    for (int oct = 0; oct < 4; ++oct) {
#pragma unroll
        for (int r = 0; r < 4; ++r) {
            const int oc = oct * 16 + ((lane >> 4) & 3) * 4 + r;
            ob[oc * HWn] = acc[oct][r] + bias[oc];
        }
    }
}

// ============================ fallback (R1 single-kernel, if ws too small) ====
__global__ __launch_bounds__(64) void dcn_r1(
    const float* __restrict__ x,
    const float* __restrict__ w_off,
    const float* __restrict__ b_off,
    const float* __restrict__ weight,
    const float* __restrict__ bias,
    float* __restrict__ out)
{
    const int p  = blockIdx.x * 64 + threadIdx.x;
    const int b  = p / HWn;
    const int hw = p % HWn;
    const int ho = hw / Wn;
    const int wo = hw % Wn;
    const float* xb = x + b * (Cn * HWn);

    float om[OFFCn];
#pragma unroll
    for (int j = 0; j < OFFCn; ++j) om[j] = b_off[j];

    int   toff[Kn];
    float tval[Kn];
#pragma unroll
    for (int ki = 0; ki < Kn; ++ki) {
        const int yy = ho + ki / 3 - 1, xx = wo + ki % 3 - 1;
        const bool v = (yy >= 0) && (yy < Hn) && (xx >= 0) && (xx < Wn);
        toff[ki] = min(max(yy, 0), Hn - 1) * Wn + min(max(xx, 0), Wn - 1);
        tval[ki] = v ? 1.0f : 0.0f;
    }
    for (int c = 0; c < Cn; ++c) {
        const float* xc = xb + c * HWn;
        float xk[Kn];
#pragma unroll
        for (int ki = 0; ki < Kn; ++ki) xk[ki] = xc[toff[ki]] * tval[ki];
        const float* wc = w_off + c * Kn;
#pragma unroll
        for (int och = 0; och < OFFCn; ++och) {
            const float* wp = wc + och * (Cn * Kn);
            float a = om[och];
#pragma unroll
            for (int ki = 0; ki < Kn; ++ki) a = fmaf(xk[ki], wp[ki], a);
            om[och] = a;
        }
    }
    float pw0[Kn], pw1[Kn], pw2[Kn], pw3[Kn];
    int   pa[Kn], pdx[Kn], pdyw[Kn];
#pragma unroll
    for (int ki = 0; ki < Kn; ++ki) {
        const float py = om[ki]      + (float)(ki / 3 + ho - 1);
        const float px = om[Kn + ki] + (float)(ki % 3 + wo - 1);
        const float m  = 1.0f / (1.0f + __expf(-om[2 * Kn + ki]));
        const float y0f = floorf(py), x0f = floorf(px);
        const float ly = py - y0f, lx = px - x0f;
        const int iy0 = (int)y0f, ix0 = (int)x0f;
        const int iy1 = iy0 + 1,  ix1 = ix0 + 1;
        const float vy0 = (iy0 >= 0 && iy0 < Hn) ? 1.0f : 0.0f;
        const float vy1 = (iy1 >= 0 && iy1 < Hn) ? 1.0f : 0.0f;
        const float vx0 = (ix0 >= 0 && ix0 < Wn) ? 1.0f : 0.0f;
        const float vx1 = (ix1 >= 0 && ix1 < Wn) ? 1.0f : 0.0f;
        const int iy0c = min(max(iy0, 0), Hn - 1);
        const int iy1c = min(max(iy1, 0), Hn - 1);
        const int ix0c = min(max(ix0, 0), Wn - 1);
        const int ix1c = min(max(ix1, 0), Wn - 1);
        pw0[ki] = m * (1.0f - ly) * (1.0f - lx) * vy0 * vx0;
        pw1[ki] = m * (1.0f - ly) * lx          * vy0 * vx1;
        pw2[ki] = m * ly          * (1.0f - lx) * vy1 * vx0;
        pw3[ki] = m * ly          * lx          * vy1 * vx1;
        pa[ki]   = iy0c * Wn + ix0c;
        pdx[ki]  = ix1c - ix0c;
        pdyw[ki] = (iy1c - iy0c) * Wn;
    }
    float acc[OCn];
#pragma unroll
    for (int oc = 0; oc < OCn; ++oc) acc[oc] = bias[oc];
    for (int c = 0; c < Cn; ++c) {
        const float* xc = xb + c * HWn;
        float s[Kn];
#pragma unroll
        for (int ki = 0; ki < Kn; ++ki) {
            const float* bp = xc + pa[ki];
            s[ki] = pw0[ki] * bp[0] + pw1[ki] * bp[pdx[ki]]
                  + pw2[ki] * bp[pdyw[ki]] + pw3[ki] * bp[pdyw[ki] + pdx[ki]];
        }
        const float* wc = weight + c * Kn;
#pragma unroll
        for (int oc = 0; oc < OCn; ++oc) {
            const float* wp = wc + oc * (Cn * Kn);
            float a = acc[oc];
#pragma unroll
            for (int ki = 0; ki < Kn; ++ki) a = fmaf(s[ki], wp[ki], a);
            acc[oc] = a;
        }
    }
    float* ob = out + b * (OCn * HWn) + hw;
#pragma unroll
    for (int oc = 0; oc < OCn; ++oc) ob[oc * HWn] = acc[oc];
}

extern "C" void kernel_launch(void* const* d_in, const int* in_sizes, int n_in,
                              void* d_out, int out_size, void* d_ws, size_t ws_size,
                              hipStream_t stream) {
    const float* x      = (const float*)d_in[0];
    const float* w_off  = (const float*)d_in[1];
    const float* b_off  = (const float*)d_in[2];
    const float* weight = (const float*)d_in[3];
    const float* bias   = (const float*)d_in[4];
    float* out = (float*)d_out;

    if (ws_size >= WS_BYTES) {
        float* wpk1  = (float*)d_ws;
        short* wpk2m = (short*)(wpk1 + WPK1_N);
        hipLaunchKernelGGL(dcn_wprep, dim3(64), dim3(256), 0, stream,
                           w_off, weight, wpk1, wpk2m);
        hipLaunchKernelGGL(dcn_fused, dim3(PGRPS), dim3(256), 0, stream,
                           x, wpk1, b_off, wpk2m, bias, out);
    } else {
        hipLaunchKernelGGL(dcn_r1, dim3(NPIX / 64), dim3(64), 0, stream,
                           x, w_off, b_off, weight, bias, out);
    }
}

// Round 16
// 346.164 us; speedup vs baseline: 1.9249x; 1.9249x over previous
//
#include <hip/hip_runtime.h>
#include <math.h>

#define Bn 8
#define Cn 64
#define Hn 96
#define Wn 96
#define HWn (Hn*Wn)
#define OCn 64
#define Kn 9
#define OFFCn 27
#define NPIX (Bn*HWn)        // 73728 = 1152*64
#define PGRPS (NPIX/64)      // 1152 pixel groups
#define BLK_PER_B (HWn/64)   // 144 blocks per batch image = PGRPS/8

// ws layout (dwords): wpk1[15552] | wpk2m[131072 shorts]
#define WPK1_N 15552
#define WPK2M_SHORTS 131072
#define WS_DWORDS (WPK1_N + WPK2M_SHORTS/2)
#define WS_BYTES  ((size_t)WS_DWORDS*4)   // ~320 KB

typedef __attribute__((ext_vector_type(8))) short short8v;
typedef __attribute__((ext_vector_type(4))) float f32x4;

static __device__ __forceinline__ unsigned short bf16_rne(float f) {
    unsigned int u = __float_as_uint(f);
    return (unsigned short)((u + 0x7FFFu + ((u >> 16) & 1u)) >> 16);
}
static __device__ __forceinline__ float bf16_back(unsigned short h) {
    return __uint_as_float(((unsigned int)h) << 16);
}

// ============ wprep: wpk1 stream (offset conv) + wpk2m MFMA A-frags ===========
__global__ __launch_bounds__(256) void dcn_wprep(
    const float* __restrict__ w_off,
    const float* __restrict__ weight,
    float* __restrict__ wpk1,
    short* __restrict__ wpk2m)
{
    const int g = blockIdx.x * 256 + threadIdx.x;   // 64 blocks -> 16384
    if (g < WPK1_N) {
        const int c_all = g / 243;
        const int och   = (g % 243) / 9;
        const int ki    = g % 9;
        wpk1[g] = w_off[(och * 64 + c_all) * 9 + ki];
    }
    if (g < WPK2M_SHORTS / 8) {
        const int lane = g & 63;
        const int oct  = (g >> 6) & 3;
        const int c    = g >> 8;
        const int oc   = oct * 16 + (lane & 15);
        const float* wsrc = weight + (oc * 64 + c) * 9;
        short8v v;
#pragma unroll
        for (int j = 0; j < 8; ++j) {
            const int s = ((lane >> 4) & 3) * 8 + j;
            float f = 0.0f;
            if (s <= 8)                  f = wsrc[s];
            else if (s >= 16 && s <= 24) f = wsrc[s - 16];
            v[j] = (short)bf16_rne(f);
        }
        ((short8v*)wpk2m)[g] = v;
    }
}

// ====== fused 512-thr: offset conv (8-way c-split) -> params -> MFMA ==========
// R16: same 64-px tile, 8 waves. Per-wave critical path ~halves vs R14
// (phase 1: 8ch not 16; phase 2 gather: 1ch/chunk not 2; MFMA: 2 tiles not 4).
// R7 evidence: 512-thr blocks achieve ~2x the resident-wave occupancy of
// 256-thr here. XCD swizzle kept (R14: FETCH 8x reduction).
__global__ __launch_bounds__(512, 4) void dcn_fused(
    const float* __restrict__ x,
    const float* __restrict__ wpk1,
    const float* __restrict__ b_off,
    const short* __restrict__ wpk2m,
    const float* __restrict__ bias,
    float* __restrict__ out)
{
    __shared__ short smp[32 * 64 * 8];      // 32 KB; phase-1 reduce aliases
    float* lds1 = (float*)smp;              // 4*64*27*4 = 27.6 KB <= 32 KB

    const int tid  = threadIdx.x;
    const int lane = tid & 63;
    const int wv   = tid >> 6;              // 0..7

    // XCD swizzle (1152 = 8 * 144, one image per XCD)
    const int bid = (blockIdx.x & 7) * BLK_PER_B + (blockIdx.x >> 3);

    const int p0  = bid * 64;
    const int b   = p0 / HWn;
    const int hwb = p0 % HWn;
    const int p   = p0 + lane;
    const int hw  = p % HWn;
    const int ho  = hw / Wn;
    const int wo  = hw % Wn;

    const float* xb = x + b * (Cn * HWn);

    // ---------------- Phase 1: offset conv, 8-way c-split ---------------------
    float om[OFFCn];
    {
        int   toff[Kn];
        float tval[Kn];
#pragma unroll
        for (int ki = 0; ki < Kn; ++ki) {
            const int yy = ho + ki / 3 - 1, xx = wo + ki % 3 - 1;
            const bool v = (yy >= 0) && (yy < Hn) && (xx >= 0) && (xx < Wn);
            toff[ki] = min(max(yy, 0), Hn - 1) * Wn + min(max(xx, 0), Wn - 1);
            tval[ki] = v ? 1.0f : 0.0f;
        }

#pragma unroll
        for (int j = 0; j < OFFCn; ++j) om[j] = 0.0f;

        const int cbase = __builtin_amdgcn_readfirstlane(wv * 8);
        const float* wstream = wpk1 + cbase * 243;
        for (int ci = 0; ci < 8; ++ci) {
            const float* xc = xb + (cbase + ci) * HWn;
            float xk[Kn];
#pragma unroll
            for (int ki = 0; ki < Kn; ++ki)
                xk[ki] = xc[toff[ki]] * tval[ki];

            const float* wc = wstream + ci * 243;
#pragma unroll
            for (int och = 0; och < OFFCn; ++och) {
                const float* wp = wc + och * 9;
                float a = om[och];
#pragma unroll
                for (int ki = 0; ki < Kn; ++ki)
                    a = fmaf(xk[ki], wp[ki], a);
                om[och] = a;
            }
        }

        // 8-wave tree reduce in 27.6 KB (stride 27, gcd(27,32)=1 -> no conflict)
        // A: waves 4-7 store; B: waves 0-3 accumulate then store; C: all read.
        if (wv >= 4) {
#pragma unroll
            for (int j = 0; j < OFFCn; ++j)
                lds1[((wv - 4) * 64 + lane) * OFFCn + j] = om[j];
        }
        __syncthreads();
        if (wv < 4) {
#pragma unroll
            for (int j = 0; j < OFFCn; ++j)
                om[j] += lds1[(wv * 64 + lane) * OFFCn + j];
        }
        __syncthreads();
        if (wv < 4) {
#pragma unroll
            for (int j = 0; j < OFFCn; ++j)
                lds1[(wv * 64 + lane) * OFFCn + j] = om[j];
        }
        __syncthreads();
#pragma unroll
        for (int j = 0; j < OFFCn; ++j) {
            float a = b_off[j];
#pragma unroll
            for (int ww = 0; ww < 4; ++ww)
                a += lds1[(ww * 64 + lane) * OFFCn + j];
            om[j] = a;
        }
    }

    // ---------------- Phase 1.5: sampling params (per pixel, all waves) -------
    float pw0[Kn], pw1[Kn], pw2[Kn], pw3[Kn];
    int   pav[Kn];
#pragma unroll
    for (int ki = 0; ki < Kn; ++ki) {
        const float py = om[ki]      + (float)(ki / 3 + ho - 1);
        const float px = om[Kn + ki] + (float)(ki % 3 + wo - 1);
        const float m  = 1.0f / (1.0f + __expf(-om[2 * Kn + ki]));

        const float y0f = floorf(py), x0f = floorf(px);
        const float ly = py - y0f, lx = px - x0f;
        const int iy0 = (int)y0f, ix0 = (int)x0f;
        const int iy1 = iy0 + 1,  ix1 = ix0 + 1;

        const float vy0 = (iy0 >= 0 && iy0 < Hn) ? 1.0f : 0.0f;
        const float vy1 = (iy1 >= 0 && iy1 < Hn) ? 1.0f : 0.0f;
        const float vx0 = (ix0 >= 0 && ix0 < Wn) ? 1.0f : 0.0f;
        const float vx1 = (ix1 >= 0 && ix1 < Wn) ? 1.0f : 0.0f;

        const int iy0c = min(max(iy0, 0), Hn - 1);
        const int iy1c = min(max(iy1, 0), Hn - 1);
        const int ix0c = min(max(ix0, 0), Wn - 1);
        const int ix1c = min(max(ix1, 0), Wn - 1);

        pw0[ki] = m * (1.0f - ly) * (1.0f - lx) * vy0 * vx0;
        pw1[ki] = m * (1.0f - ly) * lx          * vy0 * vx1;
        pw2[ki] = m * ly          * (1.0f - lx) * vy1 * vx0;
        pw3[ki] = m * ly          * lx          * vy1 * vx1;
        const int pa  = iy0c * Wn + ix0c;
        const int dx  = ix1c - ix0c;
        const int dyw = (iy1c - iy0c) * Wn;
        pav[ki] = pa | (dx << 16) | (dyw << 17);
    }
    __syncthreads();   // lds1 reads done before smp reuse

    // ---------------- Phase 2: gather (1 ch/wave/chunk) -> MFMA (2 tiles) -----
    f32x4 acc[2];
    acc[0] = (f32x4){0.f, 0.f, 0.f, 0.f};
    acc[1] = (f32x4){0.f, 0.f, 0.f, 0.f};

    const short8v* afrags = (const short8v*)wpk2m;
    const int pt = wv & 3;                   // px-tile
    const int oh = wv >> 2;                  // oc-half: octs {2*oh? no: oh*2}
    const int octA = oh * 2, octB = oh * 2 + 1;

    for (int chunk = 0; chunk < 8; ++chunk) {
        // gather: wave wv samples channel chunk*8 + wv for its pixel
        {
            const float* xc = xb + (chunk * 8 + wv) * HWn;
            unsigned short hi[Kn], lo[Kn];
#pragma unroll
            for (int ki = 0; ki < Kn; ++ki) {
                const int av  = pav[ki];
                const int pa  = av & 0xFFFF;
                const int dx  = (av >> 16) & 1;
                const int dyw = av >> 17;
                const float* bp = xc + pa;
                const float v = pw0[ki] * bp[0] + pw1[ki] * bp[dx]
                              + pw2[ki] * bp[dyw] + pw3[ki] * bp[dyw + dx];
                hi[ki] = bf16_rne(v);
                lo[ki] = bf16_rne(v - bf16_back(hi[ki]));
            }
            short8v h0, h1, l0, l1;
#pragma unroll
            for (int j = 0; j < 8; ++j) { h0[j] = (short)hi[j]; l0[j] = (short)lo[j]; }
            h1 = (short8v){(short)hi[8], 0, 0, 0, 0, 0, 0, 0};
            l1 = (short8v){(short)lo[8], 0, 0, 0, 0, 0, 0, 0};
            const int r0 = wv * 4;           // channel-in-chunk == wv
            *(short8v*)&smp[((r0 + 0) * 64 + lane) * 8] = h0;   // slots 0-7  hi
            *(short8v*)&smp[((r0 + 1) * 64 + lane) * 8] = h1;   // slots 8-15
            *(short8v*)&smp[((r0 + 2) * 64 + lane) * 8] = l0;   // slots 16-23 lo
            *(short8v*)&smp[((r0 + 3) * 64 + lane) * 8] = l1;   // slots 24-31
        }
        __syncthreads();

        // MFMA: wave handles px-tile pt, oc-tiles octA/octB
#pragma unroll
        for (int ks = 0; ks < 8; ++ks) {
            const short8v bfrag = *(const short8v*)
                &smp[((ks * 4 + (lane >> 4)) * 64 + pt * 16 + (lane & 15)) * 8];
            const short8v afA = afrags[(((chunk * 8 + ks) * 4) + octA) * 64 + lane];
            const short8v afB = afrags[(((chunk * 8 + ks) * 4) + octB) * 64 + lane];
            acc[0] = __builtin_amdgcn_mfma_f32_16x16x32_bf16(afA, bfrag, acc[0], 0, 0, 0);
            acc[1] = __builtin_amdgcn_mfma_f32_16x16x32_bf16(afB, bfrag, acc[1], 0, 0, 0);
        }
        __syncthreads();
    }

    // ---------------- epilogue: each wave writes its 2 oc-tiles x px-tile -----
    const int pxl = pt * 16 + (lane & 15);
    float* ob = out + b * (OCn * HWn) + hwb + pxl;
#pragma unroll
    for (int t = 0; t < 2; ++t) {
        const int oct = oh * 2 + t;
#pragma unroll
        for (int r = 0; r < 4; ++r) {
            const int oc = oct * 16 + ((lane >> 4) & 3) * 4 + r;
            ob[oc * HWn] = acc[t][r] + bias[oc];
        }
    }
}

// ============================ fallback (R1 single-kernel, if ws too small) ====
__global__ __launch_bounds__(64) void dcn_r1(
    const float* __restrict__ x,
    const float* __restrict__ w_off,
    const float* __restrict__ b_off,
    const float* __restrict__ weight,
    const float* __restrict__ bias,
    float* __restrict__ out)
{
    const int p  = blockIdx.x * 64 + threadIdx.x;
    const int b  = p / HWn;
    const int hw = p % HWn;
    const int ho = hw / Wn;
    const int wo = hw % Wn;
    const float* xb = x + b * (Cn * HWn);

    float om[OFFCn];
#pragma unroll
    for (int j = 0; j < OFFCn; ++j) om[j] = b_off[j];

    int   toff[Kn];
    float tval[Kn];
#pragma unroll
    for (int ki = 0; ki < Kn; ++ki) {
        const int yy = ho + ki / 3 - 1, xx = wo + ki % 3 - 1;
        const bool v = (yy >= 0) && (yy < Hn) && (xx >= 0) && (xx < Wn);
        toff[ki] = min(max(yy, 0), Hn - 1) * Wn + min(max(xx, 0), Wn - 1);
        tval[ki] = v ? 1.0f : 0.0f;
    }
    for (int c = 0; c < Cn; ++c) {
        const float* xc = xb + c * HWn;
        float xk[Kn];
#pragma unroll
        for (int ki = 0; ki < Kn; ++ki) xk[ki] = xc[toff[ki]] * tval[ki];
        const float* wc = w_off + c * Kn;
#pragma unroll
        for (int och = 0; och < OFFCn; ++och) {
            const float* wp = wc + och * (Cn * Kn);
            float a = om[och];
#pragma unroll
            for (int ki = 0; ki < Kn; ++ki) a = fmaf(xk[ki], wp[ki], a);
            om[och] = a;
        }
    }
    float pw0[Kn], pw1[Kn], pw2[Kn], pw3[Kn];
    int   pa[Kn], pdx[Kn], pdyw[Kn];
#pragma unroll
    for (int ki = 0; ki < Kn; ++ki) {
        const float py = om[ki]      + (float)(ki / 3 + ho - 1);
        const float px = om[Kn + ki] + (float)(ki % 3 + wo - 1);
        const float m  = 1.0f / (1.0f + __expf(-om[2 * Kn + ki]));
        const float y0f = floorf(py), x0f = floorf(px);
        const float ly = py - y0f, lx = px - x0f;
        const int iy0 = (int)y0f, ix0 = (int)x0f;
        const int iy1 = iy0 + 1,  ix1 = ix0 + 1;
        const float vy0 = (iy0 >= 0 && iy0 < Hn) ? 1.0f : 0.0f;
        const float vy1 = (iy1 >= 0 && iy1 < Hn) ? 1.0f : 0.0f;
        const float vx0 = (ix0 >= 0 && ix0 < Wn) ? 1.0f : 0.0f;
        const float vx1 = (ix1 >= 0 && ix1 < Wn) ? 1.0f : 0.0f;
        const int iy0c = min(max(iy0, 0), Hn - 1);
        const int iy1c = min(max(iy1, 0), Hn - 1);
        const int ix0c = min(max(ix0, 0), Wn - 1);
        const int ix1c = min(max(ix1, 0), Wn - 1);
        pw0[ki] = m * (1.0f - ly) * (1.0f - lx) * vy0 * vx0;
        pw1[ki] = m * (1.0f - ly) * lx          * vy0 * vx1;
        pw2[ki] = m * ly          * (1.0f - lx) * vy1 * vx0;
        pw3[ki] = m * ly          * lx          * vy1 * vx1;
        pa[ki]   = iy0c * Wn + ix0c;
        pdx[ki]  = ix1c - ix0c;
        pdyw[ki] = (iy1c - iy0c) * Wn;
    }
    float acc[OCn];
#pragma unroll
    for (int oc = 0; oc < OCn; ++oc) acc[oc] = bias[oc];
    for (int c = 0; c < Cn; ++c) {
        const float* xc = xb + c * HWn;
        float s[Kn];
#pragma unroll
        for (int ki = 0; ki < Kn; ++ki) {
            const float* bp = xc + pa[ki];
            s[ki] = pw0[ki] * bp[0] + pw1[ki] * bp[pdx[ki]]
                  + pw2[ki] * bp[pdyw[ki]] + pw3[ki] * bp[pdyw[ki] + pdx[ki]];
        }
        const float* wc = weight + c * Kn;
#pragma unroll
        for (int oc = 0; oc < OCn; ++oc) {
            const float* wp = wc + oc * (Cn * Kn);
            float a = acc[oc];
#pragma unroll
            for (int ki = 0; ki < Kn; ++ki) a = fmaf(s[ki], wp[ki], a);
            acc[oc] = a;
        }
    }
    float* ob = out + b * (OCn * HWn) + hw;
#pragma unroll
    for (int oc = 0; oc < OCn; ++oc) ob[oc * HWn] = acc[oc];
}

extern "C" void kernel_launch(void* const* d_in, const int* in_sizes, int n_in,
                              void* d_out, int out_size, void* d_ws, size_t ws_size,
                              hipStream_t stream) {
    const float* x      = (const float*)d_in[0];
    const float* w_off  = (const float*)d_in[1];
    const float* b_off  = (const float*)d_in[2];
    const float* weight = (const float*)d_in[3];
    const float* bias   = (const float*)d_in[4];
    float* out = (float*)d_out;

    if (ws_size >= WS_BYTES) {
        float* wpk1  = (float*)d_ws;
        short* wpk2m = (short*)(wpk1 + WPK1_N);
        hipLaunchKernelGGL(dcn_wprep, dim3(64), dim3(256), 0, stream,
                           w_off, weight, wpk1, wpk2m);
        hipLaunchKernelGGL(dcn_fused, dim3(PGRPS), dim3(512), 0, stream,
                           x, wpk1, b_off, wpk2m, bias, out);
    } else {
        hipLaunchKernelGGL(dcn_r1, dim3(NPIX / 64), dim3(64), 0, stream,
                           x, w_off, b_off, weight, bias, out);
    }
}